// Round 2
// baseline (118.903 us; speedup 1.0000x reference)
//
#include <hip/hip_runtime.h>
#include <hip/hip_cooperative_groups.h>
#include <cmath>

namespace cg = cooperative_groups;

// All-pairs edge MLP, N_E=1024, NIN=64, HID=128, OUT=64, fp32.
// out[i] = ((1/1023) * sum_{k!=i} tanh(A[i]+B[k])) @ W2 + b2
//   A = x@W1[:64,:],  B = x@W1[64:,:] + b1
// Rank-separated tanh via 2D Chebyshev (P=30, domain [-5.5,5.5]^2):
//   sum_k tanh(a_i+b_k) = sum_p T_p(a_i) V_p[h],  V = C @ M,
//   M_q[h] = sum_k T_q(b_k[h]).
//
// R6: single cooperative kernel — the discriminating experiment for
// "where do the non-fill ~37us go". Changes vs R5:
//  - ONE kernel (hipLaunchCooperativeKernel, 256 blocks x 512 thr) with a
//    single grid.sync() replacing the prep->combine dispatch boundary.
//  - A,B live in REGISTERS across the sync (same thread owns (row,h) in
//    both phases) -> the 2MB A/B global round-trip is gone.
//  - C is input-independent: computed ONCE on host in double, delivered
//    via 3.6KB hipMemcpyAsync (G9-blessed) -> no serial C block on GPU.
// Graph: memsetAsync(M4, 60KB) + memcpyAsync(C) + cooperative kernel.

#define N_E  1024
#define NIN  64
#define HID  128
#define OUTD 64
#define PCH  30      // Chebyshev terms per variable
#define NQ   32      // DCT-I grid: NQ+1 Lobatto points
#define S_CH 5.5f
#define NCOPY 4      // replicated moment buffers (atomic contention /4)

static constexpr float INV_S     = 1.0f / 5.5f;
static constexpr float TWO_LOG2E = 2.8853900817779268f; // 2*log2(e)

__device__ __forceinline__ float tanh_fast(float u) {
  // tanh(u) = 1 - 2/(1+exp2(u*2log2e))
  return 1.0f - 2.0f * __builtin_amdgcn_rcpf(
      1.0f + __builtin_amdgcn_exp2f(u * TWO_LOG2E));
}

__global__ __launch_bounds__(512) void fused_kernel(
    const float* __restrict__ x, const float* __restrict__ W1,
    const float* __restrict__ b1, const float* __restrict__ Cg,
    float* __restrict__ M4, const float* __restrict__ W2,
    const float* __restrict__ b2, float* __restrict__ out) {
  __shared__ union {
    struct {                       // phase 1: 62.5 KB
      float xs[4][NIN];
      float Msub[PCH][512];
    } p1;
    struct {                       // phase 2: 38.4 KB
      float Cs[PCH * PCH];
      float Ms[PCH * HID];
      float Vl[PCH * HID];
      float Sl[4][HID];
      float red[4][2][OUTD];
    } p2;
  } sm;

  const int t = threadIdx.x;
  const int b = blockIdx.x;
  const int h = t & (HID - 1), row = t >> 7;   // 4 rows/block, 1 row/thread

  // ---- phase 1: A,B into registers; Chebyshev moments of B -> M4 ----
  if (t < 4 * NIN) sm.p1.xs[t >> 6][t & 63] = x[(b * 4 + (t >> 6)) * NIN + (t & 63)];
  __syncthreads();
  float aA = 0.f, aB = 0.f;
  #pragma unroll 8
  for (int f = 0; f < NIN; ++f) {
    const float xv = sm.p1.xs[row][f];          // wave-broadcast
    aA += xv * W1[f * HID + h];                 // coalesced over h, L1-hot
    aB += xv * W1[(NIN + f) * HID + h];
  }
  aB += b1[h];
  {
    const float c = fminf(fmaxf(aB, -S_CH), S_CH) * INV_S;
    float m0 = 1.f, m1 = c;
    sm.p1.Msub[0][t] = 1.f;
    sm.p1.Msub[1][t] = c;
    const float c2x = c + c;
    #pragma unroll
    for (int q = 2; q < PCH; ++q) {
      const float m2 = c2x * m1 - m0;           // T_q recurrence straight to LDS
      sm.p1.Msub[q][t] = m2;
      m0 = m1; m1 = m2;
    }
  }
  __syncthreads();
  const int cpy = (b & (NCOPY - 1)) * (PCH * HID);
  for (int idx = t; idx < PCH * HID; idx += 512) {
    const int q = idx >> 7, hh = idx & (HID - 1);
    atomicAdd(&M4[cpy + idx],
              sm.p1.Msub[q][hh] + sm.p1.Msub[q][hh + HID] +
              sm.p1.Msub[q][hh + 2 * HID] + sm.p1.Msub[q][hh + 3 * HID]);
  }

  cg::this_grid().sync();   // moments complete device-wide; LDS reusable

  // ---- phase 2: V = C@Msum in LDS, Chebyshev eval with reg aA, out ----
  for (int idx = t; idx < PCH * PCH; idx += 512) sm.p2.Cs[idx] = Cg[idx];
  for (int idx = t; idx < PCH * HID; idx += 512)
    sm.p2.Ms[idx] = M4[idx] + M4[PCH * HID + idx] +
                    M4[2 * PCH * HID + idx] + M4[3 * PCH * HID + idx];
  __syncthreads();
  for (int idx = t; idx < PCH * HID; idx += 512) {
    const int p = idx >> 7, hh = idx & (HID - 1);
    float acc = 0.f;
    #pragma unroll
    for (int q = 0; q < PCH; ++q) acc += sm.p2.Cs[p * PCH + q] * sm.p2.Ms[q * HID + hh];
    sm.p2.Vl[idx] = acc;            // Cs broadcast, Ms stride-1: conflict-free
  }
  __syncthreads();
  {
    const float a = fminf(fmaxf(aA, -S_CH), S_CH) * INV_S;
    float t0 = 1.f, t1 = a;
    const float a2x = a + a;
    float acc = sm.p2.Vl[h] + a * sm.p2.Vl[HID + h];
    #pragma unroll
    for (int p = 2; p < PCH; ++p) {
      const float t2 = a2x * t1 - t0;
      acc += t2 * sm.p2.Vl[p * HID + h];
      t0 = t1; t1 = t2;
    }
    const float ts = tanh_fast(aA + aB);        // exact self term (k==i)
    sm.p2.Sl[row][h] = (acc - ts) * (1.f / (float)(N_E - 1));
  }
  __syncthreads();
  const int o = t & (OUTD - 1), half = (t >> 6) & 1;
  const int h0 = half * 64;
  float po = 0.f;
  #pragma unroll 16
  for (int hh = 0; hh < 64; ++hh)
    po += sm.p2.Sl[row][h0 + hh] * W2[(h0 + hh) * OUTD + o];  // coalesced, L1-hot
  sm.p2.red[row][half][o] = po;
  __syncthreads();
  if (t < 4 * OUTD) {
    const int rr = t >> 6, oo = t & (OUTD - 1);
    out[(b * 4 + rr) * OUTD + oo] = sm.p2.red[rr][0][oo] + sm.p2.red[rr][1][oo] + b2[oo];
  }
}

extern "C" void kernel_launch(void* const* d_in, const int* in_sizes, int n_in,
                              void* d_out, int out_size, void* d_ws, size_t ws_size,
                              hipStream_t stream) {
  const float* x  = (const float*)d_in[0];
  const float* W1 = (const float*)d_in[1];
  const float* b1 = (const float*)d_in[2];
  const float* W2 = (const float*)d_in[3];
  const float* b2 = (const float*)d_in[4];
  float* out = (float*)d_out;

  float* M4 = (float*)d_ws;                 // [NCOPY][PCH][HID]
  float* Cd = M4 + NCOPY * PCH * HID;       // [PCH][PCH]

  // ---- C is input-independent: compute once on host, double precision ----
  static float hC[PCH * PCH];
  static bool c_init = false;
  if (!c_init) {
    static double ctab[NQ + 1], fg[NQ + 1][NQ + 1], G[PCH][NQ + 1];
    const double PI = 3.14159265358979323846;
    for (int j = 0; j <= NQ; ++j) ctab[j] = std::cos(PI * j / NQ);
    for (int j = 0; j <= NQ; ++j)
      for (int l = 0; l <= NQ; ++l)
        fg[j][l] = std::tanh((double)S_CH * (ctab[j] + ctab[l]));
    for (int q = 0; q < PCH; ++q)
      for (int j = 0; j <= NQ; ++j) {
        double s = 0.0;
        for (int l = 0; l <= NQ; ++l) {
          const double w = (l == 0 || l == NQ) ? 0.5 : 1.0;
          s += w * fg[j][l] * std::cos(PI * q * l / NQ);
        }
        G[q][j] = s;
      }
    for (int p = 0; p < PCH; ++p)
      for (int q = 0; q < PCH; ++q) {
        double s = 0.0;
        for (int j = 0; j <= NQ; ++j) {
          const double w = (j == 0 || j == NQ) ? 0.5 : 1.0;
          s += w * G[q][j] * std::cos(PI * p * j / NQ);
        }
        const double cp = (p == 0 ? 1.0 : 2.0) / NQ;
        const double cq = (q == 0 ? 1.0 : 2.0) / NQ;
        hC[p * PCH + q] = (float)(s * cp * cq);
      }
    c_init = true;
  }

  hipMemsetAsync((void*)M4, 0, NCOPY * PCH * HID * sizeof(float), stream);
  hipMemcpyAsync((void*)Cd, hC, PCH * PCH * sizeof(float),
                 hipMemcpyHostToDevice, stream);

  void* args[] = {(void*)&x, (void*)&W1, (void*)&b1, (void*)&Cd,
                  (void*)&M4, (void*)&W2, (void*)&b2, (void*)&out};
  hipLaunchCooperativeKernel((void*)fused_kernel, dim3(N_E / 4), dim3(512),
                             args, 0, stream);
}

// Round 4
// 111.615 us; speedup vs baseline: 1.0653x; 1.0653x over previous
//
#include <hip/hip_runtime.h>
#include <hip/hip_cooperative_groups.h>

namespace cg = cooperative_groups;

// All-pairs edge MLP, N_E=1024, NIN=64, HID=128, OUT=64, fp32.
// out[i] = ((1/1023) * sum_{k!=i} tanh(A[i]+B[k])) @ W2 + b2
//   A = x@W1[:64,:],  B = x@W1[64:,:] + b1
// Rank-separated tanh via 2D Chebyshev (P=30, domain [-5.5,5.5]^2):
//   sum_k tanh(a_i+b_k) = sum_p T_p(a_i) V_p[h],  V = C @ M,
//   M_q[h] = sum_k T_q(b_k[h]).
//
// R8: fix R7's cross-XCD coherence bug (G16). R7 wrote C with normal
// stores from one block and normal-loaded it from 256 blocks after
// grid.sync() -> per-XCD L2 non-coherence -> stale/poison C -> absmax 2.
// Fix: NO global C at all. C is input-independent and ~125 KFLOP: every
// block recomputes it in its OWN LDS in phase 2 (ctab->fg->G->Cs, ~0.5us,
// scratch aliased over the Vl region; LDS still 61KB, 2 blocks/CU).
// M4 stays device-scope-atomic (R6-proven coherent).
// Graph: memsetAsync(60KB) + ONE cooperative kernel, no H2D node ->
// still discriminates R6's +41us (pageable memcpy vs coop-launch cost).

#define N_E  1024
#define NIN  64
#define HID  128
#define OUTD 64
#define PCH  30      // Chebyshev terms per variable
#define NQ   32      // DCT-I grid: NQ+1 Lobatto points
#define S_CH 5.5f
#define NCOPY 4      // replicated moment buffers (atomic contention /4)

static constexpr float INV_S     = 1.0f / 5.5f;
static constexpr float TWO_LOG2E = 2.8853900817779268f; // 2*log2(e)
static constexpr float PI_F      = 3.14159265358979323846f;

__device__ __forceinline__ float tanh_fast(float u) {
  // tanh(u) = 1 - 2/(1+exp2(u*2log2e))
  return 1.0f - 2.0f * __builtin_amdgcn_rcpf(
      1.0f + __builtin_amdgcn_exp2f(u * TWO_LOG2E));
}

__global__ __launch_bounds__(512) void fused_kernel(
    const float* __restrict__ x, const float* __restrict__ W1,
    const float* __restrict__ b1,
    float* __restrict__ M4, const float* __restrict__ W2,
    const float* __restrict__ b2, float* __restrict__ out) {
  __shared__ union {
    struct {                       // phase 1: 61 KB
      float xs[4][NIN];
      float Msub[PCH][512];
    } p1;
    struct {                       // phase 2: ~38 KB
      float Cs[PCH * PCH];
      float Ms[PCH * HID];
      union {
        float Vl[PCH * HID];       // 15 KB
        struct {                   // C-build scratch, 8.7 KB (dead before Vl)
          float ctab[NQ + 1];
          float fg[(NQ + 1) * (NQ + 2)];
          float G[PCH * (NQ + 2)];
        } w;
      } u;
      float Sl[4][HID];
      float red[4][2][OUTD];
    } p2;
  } sm;

  const int t = threadIdx.x;
  const int b = blockIdx.x;
  const int h = t & (HID - 1), row = t >> 7;   // 4 rows/block, 1 row/thread
  float aA = 0.f, aB = 0.f;                    // live across grid sync

  // ---- phase 1: A,B into registers; Chebyshev moments of B -> M4 ----
  if (t < 4 * NIN) sm.p1.xs[t >> 6][t & 63] = x[(b * 4 + (t >> 6)) * NIN + (t & 63)];
  __syncthreads();
  #pragma unroll 8
  for (int f = 0; f < NIN; ++f) {
    const float xv = sm.p1.xs[row][f];          // wave-broadcast
    aA += xv * W1[f * HID + h];                 // coalesced over h, L1-hot
    aB += xv * W1[(NIN + f) * HID + h];
  }
  aB += b1[h];
  {
    const float c = fminf(fmaxf(aB, -S_CH), S_CH) * INV_S;
    float m0 = 1.f, m1 = c;
    sm.p1.Msub[0][t] = 1.f;
    sm.p1.Msub[1][t] = c;
    const float c2x = c + c;
    #pragma unroll
    for (int q = 2; q < PCH; ++q) {
      const float m2 = c2x * m1 - m0;           // T_q recurrence straight to LDS
      sm.p1.Msub[q][t] = m2;
      m0 = m1; m1 = m2;
    }
  }
  __syncthreads();
  const int cpy = (b & (NCOPY - 1)) * (PCH * HID);
  for (int idx = t; idx < PCH * HID; idx += 512) {
    const int q = idx >> 7, hh = idx & (HID - 1);
    atomicAdd(&M4[cpy + idx],                   // device-scope: coherent (G12)
              sm.p1.Msub[q][hh] + sm.p1.Msub[q][hh + HID] +
              sm.p1.Msub[q][hh + 2 * HID] + sm.p1.Msub[q][hh + 3 * HID]);
  }

  cg::this_grid().sync();   // moments complete device-wide; LDS reusable

  // ---- phase 2a: per-block C rebuild in LDS (input-independent, ~0.5us) ----
  if (t <= NQ) sm.p2.u.w.ctab[t] = cosf((float)t * (PI_F / (float)NQ));
  __syncthreads();
  for (int idx = t; idx < (NQ + 1) * (NQ + 1); idx += 512) {
    const int j = idx / (NQ + 1), l = idx % (NQ + 1);
    sm.p2.u.w.fg[j * (NQ + 2) + l] =
        tanh_fast(S_CH * (sm.p2.u.w.ctab[j] + sm.p2.u.w.ctab[l]));
  }
  __syncthreads();
  // G[q][j] = sum_l w_l fg[j][l] cos(q l pi/NQ)  (cos via recurrence)
  for (int idx = t; idx < PCH * (NQ + 1); idx += 512) {
    const int q = idx / (NQ + 1), j = idx % (NQ + 1);
    const float cphi = sm.p2.u.w.ctab[q];
    float c0 = 1.f, c1 = cphi;
    float s = 0.5f * sm.p2.u.w.fg[j * (NQ + 2) + 0];   // l=0: w=1/2, cos=1
    for (int l = 1; l <= NQ; ++l) {
      const float w = (l == NQ) ? 0.5f : 1.0f;
      s += w * sm.p2.u.w.fg[j * (NQ + 2) + l] * c1;
      const float c2 = 2.f * cphi * c1 - c0; c0 = c1; c1 = c2;
    }
    sm.p2.u.w.G[q * (NQ + 2) + j] = s;
  }
  __syncthreads();
  // Cs[p][q] = cp cq sum_j w_j G[q][j] cos(p j pi/NQ); Ms = sum of M4 copies
  for (int idx = t; idx < PCH * PCH; idx += 512) {
    const int p = idx / PCH, q = idx % PCH;
    const float cphi = sm.p2.u.w.ctab[p];
    float c0 = 1.f, c1 = cphi;
    float s = 0.5f * sm.p2.u.w.G[q * (NQ + 2) + 0];
    for (int j = 1; j <= NQ; ++j) {
      const float w = (j == NQ) ? 0.5f : 1.0f;
      s += w * sm.p2.u.w.G[q * (NQ + 2) + j] * c1;
      const float c2 = 2.f * cphi * c1 - c0; c0 = c1; c1 = c2;
    }
    const float cp = (p == 0 ? 1.f : 2.f) / (float)NQ;
    const float cq = (q == 0 ? 1.f : 2.f) / (float)NQ;
    sm.p2.Cs[p * PCH + q] = s * cp * cq;
  }
  for (int idx = t; idx < PCH * HID; idx += 512)
    sm.p2.Ms[idx] = M4[idx] + M4[PCH * HID + idx] +
                    M4[2 * PCH * HID + idx] + M4[3 * PCH * HID + idx];
  __syncthreads();

  // ---- phase 2b: V = C@Msum in LDS (Vl overwrites dead C-scratch) ----
  for (int idx = t; idx < PCH * HID; idx += 512) {
    const int p = idx >> 7, hh = idx & (HID - 1);
    float acc = 0.f;
    #pragma unroll
    for (int q = 0; q < PCH; ++q) acc += sm.p2.Cs[p * PCH + q] * sm.p2.Ms[q * HID + hh];
    sm.p2.u.Vl[idx] = acc;          // Cs broadcast, Ms stride-1: conflict-free
  }
  __syncthreads();
  {
    const float a = fminf(fmaxf(aA, -S_CH), S_CH) * INV_S;
    float t0 = 1.f, t1 = a;
    const float a2x = a + a;
    float acc = sm.p2.u.Vl[h] + a * sm.p2.u.Vl[HID + h];
    #pragma unroll
    for (int p = 2; p < PCH; ++p) {
      const float t2 = a2x * t1 - t0;
      acc += t2 * sm.p2.u.Vl[p * HID + h];
      t0 = t1; t1 = t2;
    }
    const float ts = tanh_fast(aA + aB);        // exact self term (k==i)
    sm.p2.Sl[row][h] = (acc - ts) * (1.f / (float)(N_E - 1));
  }
  __syncthreads();
  const int o = t & (OUTD - 1), half = (t >> 6) & 1;
  const int h0 = half * 64;
  float po = 0.f;
  #pragma unroll 16
  for (int hh = 0; hh < 64; ++hh)
    po += sm.p2.Sl[row][h0 + hh] * W2[(h0 + hh) * OUTD + o];  // coalesced, L1-hot
  sm.p2.red[row][half][o] = po;
  __syncthreads();
  if (t < 4 * OUTD) {
    const int rr = t >> 6, oo = t & (OUTD - 1);
    out[(b * 4 + rr) * OUTD + oo] = sm.p2.red[rr][0][oo] + sm.p2.red[rr][1][oo] + b2[oo];
  }
}

extern "C" void kernel_launch(void* const* d_in, const int* in_sizes, int n_in,
                              void* d_out, int out_size, void* d_ws, size_t ws_size,
                              hipStream_t stream) {
  const float* x  = (const float*)d_in[0];
  const float* W1 = (const float*)d_in[1];
  const float* b1 = (const float*)d_in[2];
  const float* W2 = (const float*)d_in[3];
  const float* b2 = (const float*)d_in[4];
  float* out = (float*)d_out;

  float* M4 = (float*)d_ws;                 // [NCOPY][PCH][HID]

  hipMemsetAsync((void*)M4, 0, NCOPY * PCH * HID * sizeof(float), stream);

  void* args[] = {(void*)&x, (void*)&W1, (void*)&b1,
                  (void*)&M4, (void*)&W2, (void*)&b2, (void*)&out};
  hipLaunchCooperativeKernel((void*)fused_kernel, dim3(N_E / 4), dim3(512),
                             args, 0, stream);
}

// Round 5
// 89.074 us; speedup vs baseline: 1.3349x; 1.2530x over previous
//
#include <hip/hip_runtime.h>

// All-pairs edge MLP, N_E=1024, NIN=64, HID=128, OUT=64, fp32.
// out[i] = ((1/1023) * sum_{k!=i} tanh(A[i]+B[k])) @ W2 + b2
//   A = x@W1[:64,:],  B = x@W1[64:,:] + b1
// Rank-separated tanh via 2D Chebyshev (P=30, domain [-5.5,5.5]^2):
//   sum_k tanh(a_i+b_k) = sum_p T_p(a_i) V_p[h],  V = C @ M,
//   M_q[h] = sum_k T_q(b_k[h]).
//
// R9: same single-kernel dataflow as R8 (registers live across the device
// sync; per-block C rebuild in LDS; M4 via device atomics - all proven
// correct, absmax 0.0078125) but WITHOUT cooperative launch. R8's counters
// showed the phases cost ~8-11us of real work while the coop kernel
// measured 41.6us (VALUBusy 9%) -> ~30us is grid.sync + coop replay
// overhead. Replace grid.sync with a hand-rolled device-scope barrier:
//   release atomic_fetch_add on a workspace counter + acquire spin load,
//   M4 gathered with agent-scope atomic loads (G16 recipe: inter-workgroup
//   comm via device-scope atomics/fences only; no plain-store handoff).
// Regular launch, grid=256 blocks x 512 thr = 1 block/CU on 256 CUs
// (co-resident by capacity; __launch_bounds__ declared) -> no deadlock.
// Graph: memsetAsync(60KB+4) + ONE regular kernel.

#define N_E  1024
#define NIN  64
#define HID  128
#define OUTD 64
#define PCH  30      // Chebyshev terms per variable
#define NQ   32      // DCT-I grid: NQ+1 Lobatto points
#define S_CH 5.5f
#define NCOPY 4      // replicated moment buffers (atomic contention /4)
#define NBLK (N_E / 4)

static constexpr float INV_S     = 1.0f / 5.5f;
static constexpr float TWO_LOG2E = 2.8853900817779268f; // 2*log2(e)
static constexpr float PI_F      = 3.14159265358979323846f;

__device__ __forceinline__ float tanh_fast(float u) {
  // tanh(u) = 1 - 2/(1+exp2(u*2log2e))
  return 1.0f - 2.0f * __builtin_amdgcn_rcpf(
      1.0f + __builtin_amdgcn_exp2f(u * TWO_LOG2E));
}

__global__ __launch_bounds__(512) void fused2_kernel(
    const float* __restrict__ x, const float* __restrict__ W1,
    const float* __restrict__ b1,
    float* __restrict__ M4, unsigned int* __restrict__ cnt,
    const float* __restrict__ W2, const float* __restrict__ b2,
    float* __restrict__ out) {
  __shared__ union {
    struct {                       // phase 1: 61 KB
      float xs[4][NIN];
      float Msub[PCH][512];
    } p1;
    struct {                       // phase 2: ~38 KB
      float Cs[PCH * PCH];
      float Ms[PCH * HID];
      union {
        float Vl[PCH * HID];       // 15 KB
        struct {                   // C-build scratch, 8.7 KB (dead before Vl)
          float ctab[NQ + 1];
          float fg[(NQ + 1) * (NQ + 2)];
          float G[PCH * (NQ + 2)];
        } w;
      } u;
      float Sl[4][HID];
      float red[4][2][OUTD];
    } p2;
  } sm;

  const int t = threadIdx.x;
  const int b = blockIdx.x;
  const int h = t & (HID - 1), row = t >> 7;   // 4 rows/block, 1 row/thread
  float aA = 0.f, aB = 0.f;                    // live across device barrier

  // ---- phase 1: A,B into registers; Chebyshev moments of B -> M4 ----
  if (t < 4 * NIN) sm.p1.xs[t >> 6][t & 63] = x[(b * 4 + (t >> 6)) * NIN + (t & 63)];
  __syncthreads();
  #pragma unroll 8
  for (int f = 0; f < NIN; ++f) {
    const float xv = sm.p1.xs[row][f];          // wave-broadcast
    aA += xv * W1[f * HID + h];                 // coalesced over h, L1-hot
    aB += xv * W1[(NIN + f) * HID + h];
  }
  aB += b1[h];
  {
    const float c = fminf(fmaxf(aB, -S_CH), S_CH) * INV_S;
    float m0 = 1.f, m1 = c;
    sm.p1.Msub[0][t] = 1.f;
    sm.p1.Msub[1][t] = c;
    const float c2x = c + c;
    #pragma unroll
    for (int q = 2; q < PCH; ++q) {
      const float m2 = c2x * m1 - m0;           // T_q recurrence straight to LDS
      sm.p1.Msub[q][t] = m2;
      m0 = m1; m1 = m2;
    }
  }
  __syncthreads();
  const int cpy = (b & (NCOPY - 1)) * (PCH * HID);
  for (int idx = t; idx < PCH * HID; idx += 512) {
    const int q = idx >> 7, hh = idx & (HID - 1);
    atomicAdd(&M4[cpy + idx],                   // device-scope: coherent
              sm.p1.Msub[q][hh] + sm.p1.Msub[q][hh + HID] +
              sm.p1.Msub[q][hh + 2 * HID] + sm.p1.Msub[q][hh + 3 * HID]);
  }

  // ---- device barrier: release-add counter, acquire-spin until all 256 ----
  __syncthreads();                 // drains each wave's vmcnt -> M4 adds done
  if (t == 0) {
    __hip_atomic_fetch_add(cnt, 1u, __ATOMIC_RELEASE, __HIP_MEMORY_SCOPE_AGENT);
    while (__hip_atomic_load(cnt, __ATOMIC_ACQUIRE, __HIP_MEMORY_SCOPE_AGENT)
           < (unsigned)NBLK) {
      __builtin_amdgcn_s_sleep(8); // polite spin; L3-coherent polls
    }
  }
  __syncthreads();                 // whole block released; LDS reusable

  // ---- phase 2a: per-block C rebuild in LDS (input-independent, ~1us) ----
  if (t <= NQ) sm.p2.u.w.ctab[t] = cosf((float)t * (PI_F / (float)NQ));
  __syncthreads();
  for (int idx = t; idx < (NQ + 1) * (NQ + 1); idx += 512) {
    const int j = idx / (NQ + 1), l = idx % (NQ + 1);
    sm.p2.u.w.fg[j * (NQ + 2) + l] =
        tanh_fast(S_CH * (sm.p2.u.w.ctab[j] + sm.p2.u.w.ctab[l]));
  }
  __syncthreads();
  // G[q][j] = sum_l w_l fg[j][l] cos(q l pi/NQ)  (cos via recurrence)
  for (int idx = t; idx < PCH * (NQ + 1); idx += 512) {
    const int q = idx / (NQ + 1), j = idx % (NQ + 1);
    const float cphi = sm.p2.u.w.ctab[q];
    float c0 = 1.f, c1 = cphi;
    float s = 0.5f * sm.p2.u.w.fg[j * (NQ + 2) + 0];   // l=0: w=1/2, cos=1
    for (int l = 1; l <= NQ; ++l) {
      const float w = (l == NQ) ? 0.5f : 1.0f;
      s += w * sm.p2.u.w.fg[j * (NQ + 2) + l] * c1;
      const float c2 = 2.f * cphi * c1 - c0; c0 = c1; c1 = c2;
    }
    sm.p2.u.w.G[q * (NQ + 2) + j] = s;
  }
  __syncthreads();
  // Cs[p][q] = cp cq sum_j w_j G[q][j] cos(p j pi/NQ); Ms = sum of M4 copies
  for (int idx = t; idx < PCH * PCH; idx += 512) {
    const int p = idx / PCH, q = idx % PCH;
    const float cphi = sm.p2.u.w.ctab[p];
    float c0 = 1.f, c1 = cphi;
    float s = 0.5f * sm.p2.u.w.G[q * (NQ + 2) + 0];
    for (int j = 1; j <= NQ; ++j) {
      const float w = (j == NQ) ? 0.5f : 1.0f;
      s += w * sm.p2.u.w.G[q * (NQ + 2) + j] * c1;
      const float c2 = 2.f * cphi * c1 - c0; c0 = c1; c1 = c2;
    }
    const float cp = (p == 0 ? 1.f : 2.f) / (float)NQ;
    const float cq = (q == 0 ? 1.f : 2.f) / (float)NQ;
    sm.p2.Cs[p * PCH + q] = s * cp * cq;
  }
  for (int idx = t; idx < PCH * HID; idx += 512) {
    // agent-scope atomic loads: coherent regardless of which XCD summed them
    const float m0 = __hip_atomic_load(&M4[idx], __ATOMIC_RELAXED,
                                       __HIP_MEMORY_SCOPE_AGENT);
    const float m1 = __hip_atomic_load(&M4[PCH * HID + idx], __ATOMIC_RELAXED,
                                       __HIP_MEMORY_SCOPE_AGENT);
    const float m2 = __hip_atomic_load(&M4[2 * PCH * HID + idx], __ATOMIC_RELAXED,
                                       __HIP_MEMORY_SCOPE_AGENT);
    const float m3 = __hip_atomic_load(&M4[3 * PCH * HID + idx], __ATOMIC_RELAXED,
                                       __HIP_MEMORY_SCOPE_AGENT);
    sm.p2.Ms[idx] = m0 + m1 + m2 + m3;
  }
  __syncthreads();

  // ---- phase 2b: V = C@Msum in LDS (Vl overwrites dead C-scratch) ----
  for (int idx = t; idx < PCH * HID; idx += 512) {
    const int p = idx >> 7, hh = idx & (HID - 1);
    float acc = 0.f;
    #pragma unroll
    for (int q = 0; q < PCH; ++q) acc += sm.p2.Cs[p * PCH + q] * sm.p2.Ms[q * HID + hh];
    sm.p2.u.Vl[idx] = acc;          // Cs broadcast, Ms stride-1: conflict-free
  }
  __syncthreads();
  {
    const float a = fminf(fmaxf(aA, -S_CH), S_CH) * INV_S;
    float t0 = 1.f, t1 = a;
    const float a2x = a + a;
    float acc = sm.p2.u.Vl[h] + a * sm.p2.u.Vl[HID + h];
    #pragma unroll
    for (int p = 2; p < PCH; ++p) {
      const float t2 = a2x * t1 - t0;
      acc += t2 * sm.p2.u.Vl[p * HID + h];
      t0 = t1; t1 = t2;
    }
    const float ts = tanh_fast(aA + aB);        // exact self term (k==i)
    sm.p2.Sl[row][h] = (acc - ts) * (1.f / (float)(N_E - 1));
  }
  __syncthreads();
  const int o = t & (OUTD - 1), half = (t >> 6) & 1;
  const int h0 = half * 64;
  float po = 0.f;
  #pragma unroll 16
  for (int hh = 0; hh < 64; ++hh)
    po += sm.p2.Sl[row][h0 + hh] * W2[(h0 + hh) * OUTD + o];  // coalesced, L1-hot
  sm.p2.red[row][half][o] = po;
  __syncthreads();
  if (t < 4 * OUTD) {
    const int rr = t >> 6, oo = t & (OUTD - 1);
    out[(b * 4 + rr) * OUTD + oo] = sm.p2.red[rr][0][oo] + sm.p2.red[rr][1][oo] + b2[oo];
  }
}

extern "C" void kernel_launch(void* const* d_in, const int* in_sizes, int n_in,
                              void* d_out, int out_size, void* d_ws, size_t ws_size,
                              hipStream_t stream) {
  const float* x  = (const float*)d_in[0];
  const float* W1 = (const float*)d_in[1];
  const float* b1 = (const float*)d_in[2];
  const float* W2 = (const float*)d_in[3];
  const float* b2 = (const float*)d_in[4];
  float* out = (float*)d_out;

  float* M4 = (float*)d_ws;                       // [NCOPY][PCH][HID]
  unsigned int* cnt = (unsigned int*)(M4 + NCOPY * PCH * HID);

  // zero M4 (atomic accumulators) + barrier counter in one tiny node
  hipMemsetAsync((void*)M4, 0,
                 NCOPY * PCH * HID * sizeof(float) + sizeof(unsigned int),
                 stream);

  fused2_kernel<<<NBLK, 512, 0, stream>>>(x, W1, b1, M4, cnt, W2, b2, out);
}

// Round 6
// 86.116 us; speedup vs baseline: 1.3807x; 1.0344x over previous
//
#include <hip/hip_runtime.h>

// All-pairs edge MLP, N_E=1024, NIN=64, HID=128, OUT=64, fp32.
// out[i] = ((1/1023) * sum_{k!=i} tanh(A[i]+B[k])) @ W2 + b2
//   A = x@W1[:64,:],  B = x@W1[64:,:] + b1
// Rank-separated tanh via 2D Chebyshev (P=30, domain [-5.5,5.5]^2):
//   sum_k tanh(a_i+b_k) = sum_p T_p(a_i) V_p[h],  V = C @ M,
//   M_q[h] = sum_k T_q(b_k[h]).
//
// R10: barrier-contention fix, single variable vs R9. R9 passed at 89.1us
// but the in-kernel device barrier still wastes ~30us (R8's coop kernel:
// 41.6us @ VALUBusy 9% => ~30us of wait; R9 same structure). Theory: R9's
// barrier had 256 arrival fetch_adds AND 256 spinning waves ACQUIRE-polling
// the SAME cache line every ~0.2us; arrivals queue behind the poll storm at
// the line's coherence point. Fix: split arrival counter and go-flag onto
// different 128B lines; last arriver (fetch_add returns NBLK-1) RELEASE-
// stores the flag; others poll RELAXED + s_sleep(8) then one ACQUIRE load.
// Arrivals no longer contend with polls. Everything else identical to R9.
// Graph: memsetAsync(60KB+128B) + ONE regular kernel.

#define N_E  1024
#define NIN  64
#define HID  128
#define OUTD 64
#define PCH  30      // Chebyshev terms per variable
#define NQ   32      // DCT-I grid: NQ+1 Lobatto points
#define S_CH 5.5f
#define NCOPY 4      // replicated moment buffers (atomic contention /4)
#define NBLK (N_E / 4)

static constexpr float INV_S     = 1.0f / 5.5f;
static constexpr float TWO_LOG2E = 2.8853900817779268f; // 2*log2(e)
static constexpr float PI_F      = 3.14159265358979323846f;

__device__ __forceinline__ float tanh_fast(float u) {
  // tanh(u) = 1 - 2/(1+exp2(u*2log2e))
  return 1.0f - 2.0f * __builtin_amdgcn_rcpf(
      1.0f + __builtin_amdgcn_exp2f(u * TWO_LOG2E));
}

__global__ __launch_bounds__(512) void fused2_kernel(
    const float* __restrict__ x, const float* __restrict__ W1,
    const float* __restrict__ b1,
    float* __restrict__ M4, unsigned int* __restrict__ cnt,
    unsigned int* __restrict__ flag,
    const float* __restrict__ W2, const float* __restrict__ b2,
    float* __restrict__ out) {
  __shared__ union {
    struct {                       // phase 1: 61 KB
      float xs[4][NIN];
      float Msub[PCH][512];
    } p1;
    struct {                       // phase 2: ~38 KB
      float Cs[PCH * PCH];
      float Ms[PCH * HID];
      union {
        float Vl[PCH * HID];       // 15 KB
        struct {                   // C-build scratch, 8.7 KB (dead before Vl)
          float ctab[NQ + 1];
          float fg[(NQ + 1) * (NQ + 2)];
          float G[PCH * (NQ + 2)];
        } w;
      } u;
      float Sl[4][HID];
      float red[4][2][OUTD];
    } p2;
  } sm;

  const int t = threadIdx.x;
  const int b = blockIdx.x;
  const int h = t & (HID - 1), row = t >> 7;   // 4 rows/block, 1 row/thread
  float aA = 0.f, aB = 0.f;                    // live across device barrier

  // ---- phase 1: A,B into registers; Chebyshev moments of B -> M4 ----
  if (t < 4 * NIN) sm.p1.xs[t >> 6][t & 63] = x[(b * 4 + (t >> 6)) * NIN + (t & 63)];
  __syncthreads();
  #pragma unroll 8
  for (int f = 0; f < NIN; ++f) {
    const float xv = sm.p1.xs[row][f];          // wave-broadcast
    aA += xv * W1[f * HID + h];                 // coalesced over h, L1-hot
    aB += xv * W1[(NIN + f) * HID + h];
  }
  aB += b1[h];
  {
    const float c = fminf(fmaxf(aB, -S_CH), S_CH) * INV_S;
    float m0 = 1.f, m1 = c;
    sm.p1.Msub[0][t] = 1.f;
    sm.p1.Msub[1][t] = c;
    const float c2x = c + c;
    #pragma unroll
    for (int q = 2; q < PCH; ++q) {
      const float m2 = c2x * m1 - m0;           // T_q recurrence straight to LDS
      sm.p1.Msub[q][t] = m2;
      m0 = m1; m1 = m2;
    }
  }
  __syncthreads();
  const int cpy = (b & (NCOPY - 1)) * (PCH * HID);
  for (int idx = t; idx < PCH * HID; idx += 512) {
    const int q = idx >> 7, hh = idx & (HID - 1);
    atomicAdd(&M4[cpy + idx],                   // device-scope: coherent
              sm.p1.Msub[q][hh] + sm.p1.Msub[q][hh + HID] +
              sm.p1.Msub[q][hh + 2 * HID] + sm.p1.Msub[q][hh + 3 * HID]);
  }

  // ---- device barrier: arrival counter + SEPARATE go-flag line ----
  __syncthreads();                 // waitcnt drains this block's M4 adds
  if (t == 0) {
    const unsigned old = __hip_atomic_fetch_add(cnt, 1u, __ATOMIC_ACQ_REL,
                                                __HIP_MEMORY_SCOPE_AGENT);
    if (old == (unsigned)(NBLK - 1)) {
      // last arriver: everyone's adds are globally visible; open the gate
      __hip_atomic_store(flag, 1u, __ATOMIC_RELEASE, __HIP_MEMORY_SCOPE_AGENT);
    } else {
      while (__hip_atomic_load(flag, __ATOMIC_RELAXED,
                               __HIP_MEMORY_SCOPE_AGENT) == 0u)
        __builtin_amdgcn_s_sleep(8);            // ~0.2us polls, write-once line
      (void)__hip_atomic_load(flag, __ATOMIC_ACQUIRE, __HIP_MEMORY_SCOPE_AGENT);
    }
  }
  __syncthreads();                 // whole block released; LDS reusable

  // ---- phase 2a: per-block C rebuild in LDS (input-independent, ~1us) ----
  if (t <= NQ) sm.p2.u.w.ctab[t] = cosf((float)t * (PI_F / (float)NQ));
  __syncthreads();
  for (int idx = t; idx < (NQ + 1) * (NQ + 1); idx += 512) {
    const int j = idx / (NQ + 1), l = idx % (NQ + 1);
    sm.p2.u.w.fg[j * (NQ + 2) + l] =
        tanh_fast(S_CH * (sm.p2.u.w.ctab[j] + sm.p2.u.w.ctab[l]));
  }
  __syncthreads();
  // G[q][j] = sum_l w_l fg[j][l] cos(q l pi/NQ)  (cos via recurrence)
  for (int idx = t; idx < PCH * (NQ + 1); idx += 512) {
    const int q = idx / (NQ + 1), j = idx % (NQ + 1);
    const float cphi = sm.p2.u.w.ctab[q];
    float c0 = 1.f, c1 = cphi;
    float s = 0.5f * sm.p2.u.w.fg[j * (NQ + 2) + 0];   // l=0: w=1/2, cos=1
    for (int l = 1; l <= NQ; ++l) {
      const float w = (l == NQ) ? 0.5f : 1.0f;
      s += w * sm.p2.u.w.fg[j * (NQ + 2) + l] * c1;
      const float c2 = 2.f * cphi * c1 - c0; c0 = c1; c1 = c2;
    }
    sm.p2.u.w.G[q * (NQ + 2) + j] = s;
  }
  __syncthreads();
  // Cs[p][q] = cp cq sum_j w_j G[q][j] cos(p j pi/NQ); Ms = sum of M4 copies
  for (int idx = t; idx < PCH * PCH; idx += 512) {
    const int p = idx / PCH, q = idx % PCH;
    const float cphi = sm.p2.u.w.ctab[p];
    float c0 = 1.f, c1 = cphi;
    float s = 0.5f * sm.p2.u.w.G[q * (NQ + 2) + 0];
    for (int j = 1; j <= NQ; ++j) {
      const float w = (j == NQ) ? 0.5f : 1.0f;
      s += w * sm.p2.u.w.G[q * (NQ + 2) + j] * c1;
      const float c2 = 2.f * cphi * c1 - c0; c0 = c1; c1 = c2;
    }
    const float cp = (p == 0 ? 1.f : 2.f) / (float)NQ;
    const float cq = (q == 0 ? 1.f : 2.f) / (float)NQ;
    sm.p2.Cs[p * PCH + q] = s * cp * cq;
  }
  for (int idx = t; idx < PCH * HID; idx += 512) {
    // agent-scope atomic loads: coherent regardless of which XCD summed them
    const float m0 = __hip_atomic_load(&M4[idx], __ATOMIC_RELAXED,
                                       __HIP_MEMORY_SCOPE_AGENT);
    const float m1 = __hip_atomic_load(&M4[PCH * HID + idx], __ATOMIC_RELAXED,
                                       __HIP_MEMORY_SCOPE_AGENT);
    const float m2 = __hip_atomic_load(&M4[2 * PCH * HID + idx], __ATOMIC_RELAXED,
                                       __HIP_MEMORY_SCOPE_AGENT);
    const float m3 = __hip_atomic_load(&M4[3 * PCH * HID + idx], __ATOMIC_RELAXED,
                                       __HIP_MEMORY_SCOPE_AGENT);
    sm.p2.Ms[idx] = m0 + m1 + m2 + m3;
  }
  __syncthreads();

  // ---- phase 2b: V = C@Msum in LDS (Vl overwrites dead C-scratch) ----
  for (int idx = t; idx < PCH * HID; idx += 512) {
    const int p = idx >> 7, hh = idx & (HID - 1);
    float acc = 0.f;
    #pragma unroll
    for (int q = 0; q < PCH; ++q) acc += sm.p2.Cs[p * PCH + q] * sm.p2.Ms[q * HID + hh];
    sm.p2.u.Vl[idx] = acc;          // Cs broadcast, Ms stride-1: conflict-free
  }
  __syncthreads();
  {
    const float a = fminf(fmaxf(aA, -S_CH), S_CH) * INV_S;
    float t0 = 1.f, t1 = a;
    const float a2x = a + a;
    float acc = sm.p2.u.Vl[h] + a * sm.p2.u.Vl[HID + h];
    #pragma unroll
    for (int p = 2; p < PCH; ++p) {
      const float t2 = a2x * t1 - t0;
      acc += t2 * sm.p2.u.Vl[p * HID + h];
      t0 = t1; t1 = t2;
    }
    const float ts = tanh_fast(aA + aB);        // exact self term (k==i)
    sm.p2.Sl[row][h] = (acc - ts) * (1.f / (float)(N_E - 1));
  }
  __syncthreads();
  const int o = t & (OUTD - 1), half = (t >> 6) & 1;
  const int h0 = half * 64;
  float po = 0.f;
  #pragma unroll 16
  for (int hh = 0; hh < 64; ++hh)
    po += sm.p2.Sl[row][h0 + hh] * W2[(h0 + hh) * OUTD + o];  // coalesced, L1-hot
  sm.p2.red[row][half][o] = po;
  __syncthreads();
  if (t < 4 * OUTD) {
    const int rr = t >> 6, oo = t & (OUTD - 1);
    out[(b * 4 + rr) * OUTD + oo] = sm.p2.red[rr][0][oo] + sm.p2.red[rr][1][oo] + b2[oo];
  }
}

extern "C" void kernel_launch(void* const* d_in, const int* in_sizes, int n_in,
                              void* d_out, int out_size, void* d_ws, size_t ws_size,
                              hipStream_t stream) {
  const float* x  = (const float*)d_in[0];
  const float* W1 = (const float*)d_in[1];
  const float* b1 = (const float*)d_in[2];
  const float* W2 = (const float*)d_in[3];
  const float* b2 = (const float*)d_in[4];
  float* out = (float*)d_out;

  float* M4 = (float*)d_ws;                       // [NCOPY][PCH][HID]
  float* ctrl = M4 + NCOPY * PCH * HID;           // control area (128B-split)
  unsigned int* cnt  = (unsigned int*)ctrl;        // line 0: arrival counter
  unsigned int* flag = (unsigned int*)(ctrl + 32); // line 1 (+128B): go flag

  // zero M4 (atomic accumulators) + both control lines in one tiny node
  hipMemsetAsync((void*)M4, 0,
                 NCOPY * PCH * HID * sizeof(float) + 64 * sizeof(float),
                 stream);

  fused2_kernel<<<NBLK, 512, 0, stream>>>(x, W1, b1, M4, cnt, flag, W2, b2, out);
}